// Round 13
// baseline (208.365 us; speedup 1.0000x reference)
//
#include <hip/hip_runtime.h>

typedef __bf16 bf16x8 __attribute__((ext_vector_type(8)));
typedef float f32x4 __attribute__((ext_vector_type(4)));

#define DEV __device__ __forceinline__

DEV unsigned short f2bf(float f) {
  union { float f; unsigned u; } x; x.f = f;
  unsigned r = x.u + 0x7FFFu + ((x.u >> 16) & 1u);  // RNE
  return (unsigned short)(r >> 16);
}
DEV float bf2f(unsigned short h) {
  union { unsigned u; float f; } x; x.u = ((unsigned)h) << 16;
  return x.f;
}
DEV unsigned short bfc(float f) {  // hw cvt (RNE)
  union { __bf16 b; unsigned short u; } c; c.b = (__bf16)f; return c.u;
}

typedef __attribute__((address_space(3))) void* lds_vp;
typedef const __attribute__((address_space(1))) void* gbl_vp;
DEV void load_lds16(const unsigned short* gp, void* lp) {
  __builtin_amdgcn_global_load_lds((gbl_vp)(const void*)gp, (lds_vp)lp, 16, 0, 0);
}

// ---- fused ingest (inputs f32): convert x/rel/bo, transpose Wq|Wkv|Wo -----
__global__ __launch_bounds__(256)
void prep_k(const float* __restrict__ x, const float* __restrict__ rel,
            const float* __restrict__ bo, const float* __restrict__ Wq,
            const float* __restrict__ Wkv, const float* __restrict__ Wo,
            unsigned short* __restrict__ xb, unsigned short* __restrict__ relb,
            unsigned short* __restrict__ bob, unsigned short* __restrict__ WqkvT,
            unsigned short* __restrict__ WoT) {
  __shared__ unsigned short tile[32][33];
  const int bid = blockIdx.x, tid = threadIdx.x;
  if (bid < 2114) {
    const float* src; unsigned short* dst; long base; long n;
    if (bid < 2048)      { src = x;   dst = xb;   base = (long)bid * 1024;          n = 2097152; }
    else if (bid < 2113) { src = rel; dst = relb; base = (long)(bid - 2048) * 1024; n = 65600; }
    else                 { src = bo;  dst = bob;  base = 0;                          n = 1024; }
    long i = base + tid * 4;
    if (i < n) {
      float4 v = *(const float4*)&src[i];
      unsigned long long u = (unsigned long long)f2bf(v.x)
                           | ((unsigned long long)f2bf(v.y) << 16)
                           | ((unsigned long long)f2bf(v.z) << 32)
                           | ((unsigned long long)f2bf(v.w) << 48);
      *(unsigned long long*)&dst[i] = u;
    }
  } else {
    int id = bid - 2114;
    const float* src; unsigned short* dst; const int R = 1024; int C, txt, tyt;
    if (id < 1024)      { src = Wq;  dst = WqkvT;           C = 1024; txt = id & 31; tyt = id >> 5; }
    else if (id < 3072) { int l = id - 1024; src = Wkv; dst = WqkvT + 1048576; C = 2048; txt = l & 63; tyt = l >> 6; }
    else                { int l = id - 3072; src = Wo;  dst = WoT;             C = 1024; txt = l & 31; tyt = l >> 5; }
    int c0 = txt * 32, r0 = tyt * 32;
    int tx = tid & 31, ty = tid >> 5;
    #pragma unroll
    for (int i = 0; i < 4; ++i)
      tile[ty + i * 8][tx] = f2bf(src[(size_t)(r0 + ty + i * 8) * C + c0 + tx]);
    __syncthreads();
    #pragma unroll
    for (int i = 0; i < 4; ++i)
      dst[(size_t)(c0 + ty + i * 8) * R + r0 + tx] = tile[tx][ty + i * 8];
  }
}

// ---- XOR-8 swizzled staging/read for 64-short-row LDS tiles ---------------
DEV void stage16(const unsigned short* gbase, size_t gstride,
                 unsigned short* lbase, int r0, int lane) {
  #pragma unroll
  for (int t = 0; t < 2; ++t) {
    int r = r0 + t * 8 + (lane >> 3);
    int lc = (lane & 7) ^ (r & 7);
    load_lds16(&gbase[(size_t)r * gstride + lc * 8], &lbase[(size_t)(r0 + t * 8) * 64]);
  }
}
DEV bf16x8 read_swz(const unsigned short* buf, int row, int lc) {
  int pc = lc ^ (row & 7);
  return *(const bf16x8*)&buf[row * 64 + pc * 8];
}

// ---------------- GEMM qkv = x @ WqkvT^T — 64x128 tiles, BK=64 -------------
// 768 blocks = 3/CU; 2 barriers per 64-K (half of BK=32); swizzled staging.
__global__ __launch_bounds__(256)
void gemm_qkv(const unsigned short* __restrict__ A,
              const unsigned short* __restrict__ Bt,
              unsigned short* __restrict__ o0,   // q [b,h,n,d] *0.125
              unsigned short* __restrict__ o1,   // k [b,h,n,d]
              unsigned short* __restrict__ o2) { // vT [b,h,d,n]
  __shared__ __align__(16) unsigned short As[64 * 64];
  __shared__ __align__(16) unsigned short Bs[128 * 64];
  __shared__ unsigned short tbuf[64][68];
  const int tid  = threadIdx.x;
  const int lane = tid & 63, wave = tid >> 6;
  const int q15  = lane & 15, quad = lane >> 4;
  const int wr = wave >> 1, wc = wave & 1;
  const int m0 = blockIdx.y * 64, n0 = blockIdx.x * 128;
  const int K = 1024;

  f32x4 acc[2][4] = {};
  for (int k0 = 0; k0 < K; k0 += 64) {
    __syncthreads();
    stage16(&A[(size_t)m0 * K + k0], K, As, wave * 16, lane);
    stage16(&Bt[(size_t)n0 * K + k0], K, Bs, wave * 32, lane);
    stage16(&Bt[(size_t)n0 * K + k0], K, Bs, wave * 32 + 16, lane);
    __syncthreads();
    #pragma unroll
    for (int ks = 0; ks < 2; ++ks) {
      bf16x8 af[2], bfr[4];
      #pragma unroll
      for (int i = 0; i < 2; ++i)
        af[i] = read_swz(As, wr * 32 + i * 16 + q15, ks * 4 + quad);
      #pragma unroll
      for (int j = 0; j < 4; ++j)
        bfr[j] = read_swz(Bs, wc * 64 + j * 16 + q15, ks * 4 + quad);
      #pragma unroll
      for (int i = 0; i < 2; ++i)
        #pragma unroll
        for (int j = 0; j < 4; ++j)
          acc[i][j] = __builtin_amdgcn_mfma_f32_16x16x32_bf16(af[i], bfr[j], acc[i][j], 0, 0, 0);
    }
  }

  const int b = m0 >> 10, nn0 = m0 & 1023;
  if (n0 < 2048) {
    #pragma unroll
    for (int i = 0; i < 2; ++i)
      #pragma unroll
      for (int j = 0; j < 4; ++j)
        #pragma unroll
        for (int r = 0; r < 4; ++r) {
          int row = m0 + wr * 32 + i * 16 + quad * 4 + r;
          int col = n0 + wc * 64 + j * 16 + q15;
          float v = acc[i][j][r];
          int nn = row & 1023;
          unsigned short* dst; int c = col; float sc = 1.f;
          if (col < 1024) { dst = o0; sc = 0.125f; }
          else            { dst = o1; c = col - 1024; }
          int h = c >> 6, dd = c & 63;
          dst[((size_t)((row >> 10) * 16 + h) * 1024 + nn) * 64 + dd] = f2bf(v * sc);
        }
  } else {
    const int hp = (n0 - 2048) >> 6;
    #pragma unroll
    for (int hh = 0; hh < 2; ++hh) {
      __syncthreads();
      if (wc == hh) {
        #pragma unroll
        for (int i = 0; i < 2; ++i)
          #pragma unroll
          for (int j = 0; j < 4; ++j)
            #pragma unroll
            for (int r = 0; r < 4; ++r)
              tbuf[wr * 32 + i * 16 + quad * 4 + r][j * 16 + q15] = f2bf(acc[i][j][r]);
      }
      __syncthreads();
      const int bh = b * 16 + hp + hh;
      const int d = tid >> 2, nb = (tid & 3) * 16;
      #pragma unroll
      for (int s = 0; s < 2; ++s) {
        int n = nb + s * 8;
        union { uint4 v; unsigned short us[8]; } t;
        #pragma unroll
        for (int e = 0; e < 8; ++e) t.us[e] = tbuf[n + e][d];
        *(uint4*)&o2[((size_t)bh * 64 + d) * 1024 + nn0 + n] = t.v;
      }
    }
  }
}

// ---------------- flash attention: barrier-free, direct-L2 K/V -------------
// grid (x=bh 32 -> per-XCD KV working set 1MB = L2-resident, y=i-tile 16).
// K/V B-frags loaded straight from global into register double-buffers; all
// LDS (T,P) is per-wave -> ZERO __syncthreads. LDS 29.5 KB.
DEV void loadKV(const unsigned short* kp, const unsigned short* tp, int j0,
                int q15, int quad, bf16x8 bk[2][4], bf16x8 bv[2][4]) {
  #pragma unroll
  for (int ks = 0; ks < 2; ++ks)
    #pragma unroll
    for (int c = 0; c < 4; ++c) {
      bk[ks][c] = *(const bf16x8*)&kp[(size_t)(j0 + c * 16 + q15) * 64 + ks * 32 + quad * 8];
      bv[ks][c] = *(const bf16x8*)&tp[(size_t)(c * 16 + q15) * 1024 + j0 + ks * 32 + quad * 8];
    }
}

DEV void fstep(int j0, int ib, int q15, int quad,
               const bf16x8 aq[2], const bf16x8 bk[2][4], const bf16x8 bv[2][4],
               const unsigned short* __restrict__ rel,
               float (*T)[84], unsigned short* P,
               f32x4 o[4], float l_i[4]) {
  f32x4 accS[4] = {};
  #pragma unroll
  for (int ks = 0; ks < 2; ++ks)
    #pragma unroll
    for (int cb = 0; cb < 4; ++cb)
      accS[cb] = __builtin_amdgcn_mfma_f32_16x16x32_bf16(aq[ks], bk[ks][cb], accS[cb], 0, 0, 0);

  int tb = ib - j0 + 512 - 63;
  f32x4 accT[5] = {};
  #pragma unroll
  for (int ks = 0; ks < 2; ++ks)
    #pragma unroll
    for (int ub = 0; ub < 5; ++ub) {
      int trow = tb + ub * 16 + q15;
      trow = trow < 0 ? 0 : (trow > 1024 ? 1024 : trow);
      bf16x8 br = *(const bf16x8*)&rel[(size_t)trow * 64 + ks * 32 + quad * 8];
      accT[ub] = __builtin_amdgcn_mfma_f32_16x16x32_bf16(aq[ks], br, accT[ub], 0, 0, 0);
    }
  #pragma unroll
  for (int ub = 0; ub < 5; ++ub)
    #pragma unroll
    for (int r = 0; r < 4; ++r)
      T[quad * 4 + r][ub * 16 + q15] = accT[ub][r];

  #pragma unroll
  for (int r = 0; r < 4; ++r) {
    const int dl = quad * 4 + r;
    #pragma unroll
    for (int cb = 0; cb < 4; ++cb) {
      int dj = cb * 16 + q15;
      float s = accS[cb][r] + T[dl][63 + dl - dj];
      float p = exp2f(fmaf(s, 1.44269504f, -64.f));
      l_i[r] += p;
      P[dl * 64 + ((((dj >> 3) ^ (dl & 7)) << 3) | (dj & 7))] = bfc(p);
    }
  }

  #pragma unroll
  for (int ks = 0; ks < 2; ++ks) {
    bf16x8 ap = *(const bf16x8*)&P[q15 * 64 + (((ks * 4 + quad) ^ (q15 & 7)) << 3)];
    #pragma unroll
    for (int db = 0; db < 4; ++db)
      o[db] = __builtin_amdgcn_mfma_f32_16x16x32_bf16(ap, bv[ks][db], o[db], 0, 0, 0);
  }
}

__global__ __launch_bounds__(256)
void flash_attn(const unsigned short* __restrict__ q_ws,   // pre-scaled .125
                const unsigned short* __restrict__ k_ws,
                const unsigned short* __restrict__ vt_ws,  // [bh][64][1024]
                const unsigned short* __restrict__ rel,    // [1025][64]
                unsigned short* __restrict__ ao) {         // [2048][1024]
  __shared__ __align__(16) unsigned short P_lds[4][16 * 64];  // XOR-8 swizzled
  __shared__ __align__(16) float T_lds[4][16][84];

  const int tid  = threadIdx.x;
  const int lane = tid & 63, w = tid >> 6;
  const int q15  = lane & 15, quad = lane >> 4;
  const int bh = blockIdx.x;
  const int ib = blockIdx.y * 64 + w * 16;

  const unsigned short* qp = q_ws  + (size_t)bh * 1024 * 64;
  const unsigned short* kp = k_ws  + (size_t)bh * 1024 * 64;
  const unsigned short* tp = vt_ws + (size_t)bh * 64 * 1024;

  bf16x8 aq[2];
  #pragma unroll
  for (int ks = 0; ks < 2; ++ks)
    aq[ks] = *(const bf16x8*)&qp[(size_t)(ib + q15) * 64 + ks * 32 + quad * 8];

  f32x4 o[4] = {};
  float l_i[4] = {0.f, 0.f, 0.f, 0.f};

  bf16x8 bkA[2][4], bvA[2][4], bkB[2][4], bvB[2][4];
  loadKV(kp, tp, 0, q15, quad, bkA, bvA);

  for (int jt = 0; jt < 16; jt += 2) {
    loadKV(kp, tp, (jt + 1) * 64, q15, quad, bkB, bvB);
    fstep(jt * 64, ib, q15, quad, aq, bkA, bvA, rel, T_lds[w], P_lds[w], o, l_i);
    if (jt + 2 < 16)
      loadKV(kp, tp, (jt + 2) * 64, q15, quad, bkA, bvA);
    fstep((jt + 1) * 64, ib, q15, quad, aq, bkB, bvB, rel, T_lds[w], P_lds[w], o, l_i);
  }

  #pragma unroll
  for (int r = 0; r < 4; ++r) {
    #pragma unroll
    for (int off = 1; off < 16; off <<= 1)
      l_i[r] += __shfl_xor(l_i[r], off, 64);
    l_i[r] = 1.f / (l_i[r] + 1e-30f);
  }

  const int b = bh >> 4, h = bh & 15;
  #pragma unroll
  for (int db = 0; db < 4; ++db)
    #pragma unroll
    for (int r = 0; r < 4; ++r) {
      int row = ib + quad * 4 + r;
      ao[((size_t)(b * 1024 + row)) * 1024 + h * 64 + db * 16 + q15] =
          bfc(o[db][r] * l_i[r]);
    }
}

// ---------------- GEMM out = ao @ WoT^T + bo — 64x64 tiles, BK=64 ----------
__global__ __launch_bounds__(256)
void gemm_out(const unsigned short* __restrict__ A,
              const unsigned short* __restrict__ Bt,
              const unsigned short* __restrict__ bias,
              float* __restrict__ fo) {
  __shared__ __align__(16) unsigned short As[64 * 64];
  __shared__ __align__(16) unsigned short Bs[64 * 64];
  const int tid  = threadIdx.x;
  const int lane = tid & 63, w = tid >> 6;
  const int q15  = lane & 15, quad = lane >> 4;
  const int m0 = blockIdx.y * 64, n0 = blockIdx.x * 64;
  const int K = 1024, N = 1024;

  f32x4 acc[4] = {};
  for (int k0 = 0; k0 < K; k0 += 64) {
    __syncthreads();
    stage16(&A[(size_t)m0 * K + k0], K, As, w * 16, lane);
    stage16(&Bt[(size_t)n0 * K + k0], K, Bs, w * 16, lane);
    __syncthreads();
    #pragma unroll
    for (int ks = 0; ks < 2; ++ks) {
      bf16x8 af = read_swz(As, w * 16 + q15, ks * 4 + quad);
      bf16x8 bfr[4];
      #pragma unroll
      for (int j = 0; j < 4; ++j)
        bfr[j] = read_swz(Bs, j * 16 + q15, ks * 4 + quad);
      #pragma unroll
      for (int j = 0; j < 4; ++j)
        acc[j] = __builtin_amdgcn_mfma_f32_16x16x32_bf16(af, bfr[j], acc[j], 0, 0, 0);
    }
  }
  #pragma unroll
  for (int j = 0; j < 4; ++j)
    #pragma unroll
    for (int r = 0; r < 4; ++r) {
      int row = m0 + w * 16 + quad * 4 + r;
      int col = n0 + j * 16 + q15;
      fo[(size_t)row * N + col] = acc[j][r] + bf2f(bias[col]);
    }
}

// ---------------------------------------------------------------------------
extern "C" void kernel_launch(void* const* d_in, const int* in_sizes, int n_in,
                              void* d_out, int out_size, void* d_ws, size_t ws_size,
                              hipStream_t stream) {
  (void)in_sizes; (void)n_in; (void)out_size; (void)ws_size;
  const float* x   = (const float*)d_in[0];
  const float* Wq  = (const float*)d_in[1];
  const float* Wkv = (const float*)d_in[2];
  const float* Wo  = (const float*)d_in[3];
  const float* bo  = (const float*)d_in[4];
  const float* rel = (const float*)d_in[5];
  float* out = (float*)d_out;

  unsigned short* ws = (unsigned short*)d_ws;
  unsigned short* WoT   = ws;                      // 1,048,576
  unsigned short* relb  = WoT   + 1048576;         // 65,664 reserved
  unsigned short* bob   = relb  + 65664;           // 1,088 reserved
  unsigned short* q_ws  = bob   + 1088;            // 2,097,152
  unsigned short* k_ws  = q_ws  + 2097152;         // 2,097,152
  unsigned short* vT    = k_ws  + 2097152;         // 2,097,152
  unsigned short* WqkvT = vT    + 2097152;         // 3,145,728 (dead after gemm_qkv)
  unsigned short* xb    = WqkvT + 3145728;         // 2,097,152 (dead after gemm_qkv)
  unsigned short* ao    = WqkvT;                   // alias

  prep_k<<<6210, 256, 0, stream>>>(x, rel, bo, Wq, Wkv, Wo,
                                   xb, relb, bob, WqkvT, WoT);
  gemm_qkv<<<dim3(24, 32), 256, 0, stream>>>(xb, WqkvT, q_ws, k_ws, vT);
  flash_attn<<<dim3(32, 16), 256, 0, stream>>>(q_ws, k_ws, vT, relb, ao);
  gemm_out<<<dim3(16, 32), 256, 0, stream>>>(ao, WoT, bob, out);
}

// Round 14
// 159.302 us; speedup vs baseline: 1.3080x; 1.3080x over previous
//
#include <hip/hip_runtime.h>

typedef __bf16 bf16x8 __attribute__((ext_vector_type(8)));
typedef float f32x4 __attribute__((ext_vector_type(4)));

#define DEV __device__ __forceinline__

DEV unsigned short f2bf(float f) {
  union { float f; unsigned u; } x; x.f = f;
  unsigned r = x.u + 0x7FFFu + ((x.u >> 16) & 1u);  // RNE
  return (unsigned short)(r >> 16);
}
DEV float bf2f(unsigned short h) {
  union { unsigned u; float f; } x; x.u = ((unsigned)h) << 16;
  return x.f;
}
DEV unsigned short bfc(float f) {  // hw cvt (RNE)
  union { __bf16 b; unsigned short u; } c; c.b = (__bf16)f; return c.u;
}

typedef __attribute__((address_space(3))) void* lds_vp;
typedef const __attribute__((address_space(1))) void* gbl_vp;
DEV void load_lds16(const unsigned short* gp, void* lp) {
  __builtin_amdgcn_global_load_lds((gbl_vp)(const void*)gp, (lds_vp)lp, 16, 0, 0);
}

// ---- fused ingest (inputs f32): convert x/rel/bo, transpose Wq|Wkv|Wo -----
__global__ __launch_bounds__(256)
void prep_k(const float* __restrict__ x, const float* __restrict__ rel,
            const float* __restrict__ bo, const float* __restrict__ Wq,
            const float* __restrict__ Wkv, const float* __restrict__ Wo,
            unsigned short* __restrict__ xb, unsigned short* __restrict__ relb,
            unsigned short* __restrict__ bob, unsigned short* __restrict__ WqkvT,
            unsigned short* __restrict__ WoT) {
  __shared__ unsigned short tile[32][33];
  const int bid = blockIdx.x, tid = threadIdx.x;
  if (bid < 2114) {
    const float* src; unsigned short* dst; long base; long n;
    if (bid < 2048)      { src = x;   dst = xb;   base = (long)bid * 1024;          n = 2097152; }
    else if (bid < 2113) { src = rel; dst = relb; base = (long)(bid - 2048) * 1024; n = 65600; }
    else                 { src = bo;  dst = bob;  base = 0;                          n = 1024; }
    long i = base + tid * 4;
    if (i < n) {
      float4 v = *(const float4*)&src[i];
      unsigned long long u = (unsigned long long)f2bf(v.x)
                           | ((unsigned long long)f2bf(v.y) << 16)
                           | ((unsigned long long)f2bf(v.z) << 32)
                           | ((unsigned long long)f2bf(v.w) << 48);
      *(unsigned long long*)&dst[i] = u;
    }
  } else {
    int id = bid - 2114;
    const float* src; unsigned short* dst; const int R = 1024; int C, txt, tyt;
    if (id < 1024)      { src = Wq;  dst = WqkvT;           C = 1024; txt = id & 31; tyt = id >> 5; }
    else if (id < 3072) { int l = id - 1024; src = Wkv; dst = WqkvT + 1048576; C = 2048; txt = l & 63; tyt = l >> 6; }
    else                { int l = id - 3072; src = Wo;  dst = WoT;             C = 1024; txt = l & 31; tyt = l >> 5; }
    int c0 = txt * 32, r0 = tyt * 32;
    int tx = tid & 31, ty = tid >> 5;
    #pragma unroll
    for (int i = 0; i < 4; ++i)
      tile[ty + i * 8][tx] = f2bf(src[(size_t)(r0 + ty + i * 8) * C + c0 + tx]);
    __syncthreads();
    #pragma unroll
    for (int i = 0; i < 4; ++i)
      dst[(size_t)(c0 + ty + i * 8) * R + r0 + tx] = tile[tx][ty + i * 8];
  }
}

// ---- XOR-8 swizzled staging/read for 64-short-row LDS tiles ---------------
DEV void stage16(const unsigned short* gbase, size_t gstride,
                 unsigned short* lbase, int r0, int lane) {
  #pragma unroll
  for (int t = 0; t < 2; ++t) {
    int r = r0 + t * 8 + (lane >> 3);
    int lc = (lane & 7) ^ (r & 7);
    load_lds16(&gbase[(size_t)r * gstride + lc * 8], &lbase[(size_t)(r0 + t * 8) * 64]);
  }
}
DEV bf16x8 read_swz(const unsigned short* buf, int row, int lc) {
  int pc = lc ^ (row & 7);
  return *(const bf16x8*)&buf[row * 64 + pc * 8];
}

// ---------------- GEMM qkv = x @ WqkvT^T — 64x128 tiles, BK=64 -------------
// (R13-proven: non-flash total dropped ~11 µs with BK=64 swizzled staging)
__global__ __launch_bounds__(256)
void gemm_qkv(const unsigned short* __restrict__ A,
              const unsigned short* __restrict__ Bt,
              unsigned short* __restrict__ o0,   // q [b,h,n,d] *0.125
              unsigned short* __restrict__ o1,   // k [b,h,n,d]
              unsigned short* __restrict__ o2) { // vT [b,h,d,n]
  __shared__ __align__(16) unsigned short As[64 * 64];
  __shared__ __align__(16) unsigned short Bs[128 * 64];
  __shared__ unsigned short tbuf[64][68];
  const int tid  = threadIdx.x;
  const int lane = tid & 63, wave = tid >> 6;
  const int q15  = lane & 15, quad = lane >> 4;
  const int wr = wave >> 1, wc = wave & 1;
  const int m0 = blockIdx.y * 64, n0 = blockIdx.x * 128;
  const int K = 1024;

  f32x4 acc[2][4] = {};
  for (int k0 = 0; k0 < K; k0 += 64) {
    __syncthreads();
    stage16(&A[(size_t)m0 * K + k0], K, As, wave * 16, lane);
    stage16(&Bt[(size_t)n0 * K + k0], K, Bs, wave * 32, lane);
    stage16(&Bt[(size_t)n0 * K + k0], K, Bs, wave * 32 + 16, lane);
    __syncthreads();
    #pragma unroll
    for (int ks = 0; ks < 2; ++ks) {
      bf16x8 af[2], bfr[4];
      #pragma unroll
      for (int i = 0; i < 2; ++i)
        af[i] = read_swz(As, wr * 32 + i * 16 + q15, ks * 4 + quad);
      #pragma unroll
      for (int j = 0; j < 4; ++j)
        bfr[j] = read_swz(Bs, wc * 64 + j * 16 + q15, ks * 4 + quad);
      #pragma unroll
      for (int i = 0; i < 2; ++i)
        #pragma unroll
        for (int j = 0; j < 4; ++j)
          acc[i][j] = __builtin_amdgcn_mfma_f32_16x16x32_bf16(af[i], bfr[j], acc[i][j], 0, 0, 0);
    }
  }

  const int b = m0 >> 10, nn0 = m0 & 1023;
  if (n0 < 2048) {
    #pragma unroll
    for (int i = 0; i < 2; ++i)
      #pragma unroll
      for (int j = 0; j < 4; ++j)
        #pragma unroll
        for (int r = 0; r < 4; ++r) {
          int row = m0 + wr * 32 + i * 16 + quad * 4 + r;
          int col = n0 + wc * 64 + j * 16 + q15;
          float v = acc[i][j][r];
          int nn = row & 1023;
          unsigned short* dst; int c = col; float sc = 1.f;
          if (col < 1024) { dst = o0; sc = 0.125f; }
          else            { dst = o1; c = col - 1024; }
          int h = c >> 6, dd = c & 63;
          dst[((size_t)((row >> 10) * 16 + h) * 1024 + nn) * 64 + dd] = f2bf(v * sc);
        }
  } else {
    const int hp = (n0 - 2048) >> 6;
    #pragma unroll
    for (int hh = 0; hh < 2; ++hh) {
      __syncthreads();
      if (wc == hh) {
        #pragma unroll
        for (int i = 0; i < 2; ++i)
          #pragma unroll
          for (int j = 0; j < 4; ++j)
            #pragma unroll
            for (int r = 0; r < 4; ++r)
              tbuf[wr * 32 + i * 16 + quad * 4 + r][j * 16 + q15] = f2bf(acc[i][j][r]);
      }
      __syncthreads();
      const int bh = b * 16 + hp + hh;
      const int d = tid >> 2, nb = (tid & 3) * 16;
      #pragma unroll
      for (int s = 0; s < 2; ++s) {
        int n = nb + s * 8;
        union { uint4 v; unsigned short us[8]; } t;
        #pragma unroll
        for (int e = 0; e < 8; ++e) t.us[e] = tbuf[n + e][d];
        *(uint4*)&o2[((size_t)bh * 64 + d) * 1024 + nn0 + n] = t.v;
      }
    }
  }
}

// ---------------- flash attention: dbuf LDS staging, f32 LDS-T, XOR-P ------
// EXACT R10/R11 structure (proven 54.7 µs). Direct-global K/V frags are
// 20x L2-request-amplified (R13: 103 µs) — LDS staging is load-bearing.
__global__ __launch_bounds__(256)
void flash_attn(const unsigned short* __restrict__ q_ws,   // pre-scaled .125
                const unsigned short* __restrict__ k_ws,
                const unsigned short* __restrict__ vt_ws,  // [bh][64][1024]
                const unsigned short* __restrict__ rel,    // [1025][64]
                unsigned short* __restrict__ ao) {         // [2048][1024]
  __shared__ __align__(16) unsigned short Kbuf[2][64 * 64];
  __shared__ __align__(16) unsigned short Vbuf[2][64 * 64];
  __shared__ __align__(16) unsigned short P_lds[4][16 * 64];  // XOR-8 swizzled
  __shared__ __align__(16) float T_lds[4][16][84];            // f32 band

  const int tid  = threadIdx.x;
  const int lane = tid & 63, w = tid >> 6;
  const int q15  = lane & 15, quad = lane >> 4;
  const int bh = blockIdx.x;
  const int ib = blockIdx.y * 64 + w * 16;

  const unsigned short* qp = q_ws  + (size_t)bh * 1024 * 64;
  const unsigned short* kp = k_ws  + (size_t)bh * 1024 * 64;
  const unsigned short* tp = vt_ws + (size_t)bh * 64 * 1024;

  bf16x8 aq[2];
  #pragma unroll
  for (int ks = 0; ks < 2; ++ks)
    aq[ks] = *(const bf16x8*)&qp[(size_t)(ib + q15) * 64 + ks * 32 + quad * 8];

  f32x4 o[4] = {};
  float l_i[4] = {0.f, 0.f, 0.f, 0.f};

  stage16(kp, 64, &Kbuf[0][0], w * 16, lane);
  stage16(tp, 1024, &Vbuf[0][0], w * 16, lane);

  for (int jt = 0; jt < 16; ++jt) {
    const int j0 = jt * 64, cur = jt & 1;
    __syncthreads();
    if (jt + 1 < 16) {
      stage16(kp + (size_t)(j0 + 64) * 64, 64, &Kbuf[cur ^ 1][0], w * 16, lane);
      stage16(tp + (j0 + 64), 1024, &Vbuf[cur ^ 1][0], w * 16, lane);
    }

    f32x4 accS[4] = {};
    #pragma unroll
    for (int ks = 0; ks < 2; ++ks)
      #pragma unroll
      for (int cb = 0; cb < 4; ++cb) {
        bf16x8 bk = read_swz(&Kbuf[cur][0], cb * 16 + q15, ks * 4 + quad);
        accS[cb] = __builtin_amdgcn_mfma_f32_16x16x32_bf16(aq[ks], bk, accS[cb], 0, 0, 0);
      }
    int tb = ib - j0 + 512 - 63;
    f32x4 accT[5] = {};
    #pragma unroll
    for (int ks = 0; ks < 2; ++ks)
      #pragma unroll
      for (int ub = 0; ub < 5; ++ub) {
        int trow = tb + ub * 16 + q15;
        trow = trow < 0 ? 0 : (trow > 1024 ? 1024 : trow);
        bf16x8 br = *(const bf16x8*)&rel[(size_t)trow * 64 + ks * 32 + quad * 8];
        accT[ub] = __builtin_amdgcn_mfma_f32_16x16x32_bf16(aq[ks], br, accT[ub], 0, 0, 0);
      }
    #pragma unroll
    for (int ub = 0; ub < 5; ++ub)
      #pragma unroll
      for (int r = 0; r < 4; ++r)
        T_lds[w][quad * 4 + r][ub * 16 + q15] = accT[ub][r];

    #pragma unroll
    for (int r = 0; r < 4; ++r) {
      const int dl = quad * 4 + r;
      #pragma unroll
      for (int cb = 0; cb < 4; ++cb) {
        int dj = cb * 16 + q15;
        float s = accS[cb][r] + T_lds[w][dl][63 + dl - dj];
        float p = exp2f(fmaf(s, 1.44269504f, -64.f));
        l_i[r] += p;
        P_lds[w][dl * 64 + ((((dj >> 3) ^ (dl & 7)) << 3) | (dj & 7))] = bfc(p);
      }
    }

    #pragma unroll
    for (int ks = 0; ks < 2; ++ks) {
      bf16x8 ap = *(const bf16x8*)&P_lds[w][q15 * 64 + (((ks * 4 + quad) ^ (q15 & 7)) << 3)];
      #pragma unroll
      for (int db = 0; db < 4; ++db) {
        bf16x8 bv = read_swz(&Vbuf[cur][0], db * 16 + q15, ks * 4 + quad);
        o[db] = __builtin_amdgcn_mfma_f32_16x16x32_bf16(ap, bv, o[db], 0, 0, 0);
      }
    }
  }

  #pragma unroll
  for (int r = 0; r < 4; ++r) {
    #pragma unroll
    for (int off = 1; off < 16; off <<= 1)
      l_i[r] += __shfl_xor(l_i[r], off, 64);
    l_i[r] = 1.f / (l_i[r] + 1e-30f);
  }

  const int b = bh >> 4, h = bh & 15;
  #pragma unroll
  for (int db = 0; db < 4; ++db)
    #pragma unroll
    for (int r = 0; r < 4; ++r) {
      int row = ib + quad * 4 + r;
      ao[((size_t)(b * 1024 + row)) * 1024 + h * 64 + db * 16 + q15] =
          bfc(o[db][r] * l_i[r]);
    }
}

// ---------------- GEMM out = ao @ WoT^T + bo — 64x64 tiles, BK=64 ----------
__global__ __launch_bounds__(256)
void gemm_out(const unsigned short* __restrict__ A,
              const unsigned short* __restrict__ Bt,
              const unsigned short* __restrict__ bias,
              float* __restrict__ fo) {
  __shared__ __align__(16) unsigned short As[64 * 64];
  __shared__ __align__(16) unsigned short Bs[64 * 64];
  const int tid  = threadIdx.x;
  const int lane = tid & 63, w = tid >> 6;
  const int q15  = lane & 15, quad = lane >> 4;
  const int m0 = blockIdx.y * 64, n0 = blockIdx.x * 64;
  const int K = 1024, N = 1024;

  f32x4 acc[4] = {};
  for (int k0 = 0; k0 < K; k0 += 64) {
    __syncthreads();
    stage16(&A[(size_t)m0 * K + k0], K, As, w * 16, lane);
    stage16(&Bt[(size_t)n0 * K + k0], K, Bs, w * 16, lane);
    __syncthreads();
    #pragma unroll
    for (int ks = 0; ks < 2; ++ks) {
      bf16x8 af = read_swz(As, w * 16 + q15, ks * 4 + quad);
      bf16x8 bfr[4];
      #pragma unroll
      for (int j = 0; j < 4; ++j)
        bfr[j] = read_swz(Bs, j * 16 + q15, ks * 4 + quad);
      #pragma unroll
      for (int j = 0; j < 4; ++j)
        acc[j] = __builtin_amdgcn_mfma_f32_16x16x32_bf16(af, bfr[j], acc[j], 0, 0, 0);
    }
  }
  #pragma unroll
  for (int j = 0; j < 4; ++j)
    #pragma unroll
    for (int r = 0; r < 4; ++r) {
      int row = m0 + w * 16 + quad * 4 + r;
      int col = n0 + j * 16 + q15;
      fo[(size_t)row * N + col] = acc[j][r] + bf2f(bias[col]);
    }
}

// ---------------------------------------------------------------------------
extern "C" void kernel_launch(void* const* d_in, const int* in_sizes, int n_in,
                              void* d_out, int out_size, void* d_ws, size_t ws_size,
                              hipStream_t stream) {
  (void)in_sizes; (void)n_in; (void)out_size; (void)ws_size;
  const float* x   = (const float*)d_in[0];
  const float* Wq  = (const float*)d_in[1];
  const float* Wkv = (const float*)d_in[2];
  const float* Wo  = (const float*)d_in[3];
  const float* bo  = (const float*)d_in[4];
  const float* rel = (const float*)d_in[5];
  float* out = (float*)d_out;

  unsigned short* ws = (unsigned short*)d_ws;
  unsigned short* WoT   = ws;                      // 1,048,576
  unsigned short* relb  = WoT   + 1048576;         // 65,664 reserved
  unsigned short* bob   = relb  + 65664;           // 1,088 reserved
  unsigned short* q_ws  = bob   + 1088;            // 2,097,152
  unsigned short* k_ws  = q_ws  + 2097152;         // 2,097,152
  unsigned short* vT    = k_ws  + 2097152;         // 2,097,152
  unsigned short* WqkvT = vT    + 2097152;         // 3,145,728 (dead after gemm_qkv)
  unsigned short* xb    = WqkvT + 3145728;         // 2,097,152 (dead after gemm_qkv)
  unsigned short* ao    = WqkvT;                   // alias

  prep_k<<<6210, 256, 0, stream>>>(x, rel, bo, Wq, Wkv, Wo,
                                   xb, relb, bob, WqkvT, WoT);
  gemm_qkv<<<dim3(24, 32), 256, 0, stream>>>(xb, WqkvT, q_ws, k_ws, vT);
  flash_attn<<<dim3(32, 16), 256, 0, stream>>>(q_ws, k_ws, vT, relb, ao);
  gemm_out<<<dim3(16, 32), 256, 0, stream>>>(ao, WoT, bob, out);
}